// Round 3
// baseline (117.322 us; speedup 1.0000x reference)
//
#include <hip/hip_runtime.h>

// InvWarpFlow: out[b,y,x,c] = bilinear(img[b], (y + flow[b,y,x,0], x + flow[b,y,x,1]))
// (reference is dense_image_warp(img, -flow), so query = grid + flow)
// img:  [16,256,512,32] f32
// flow: [16,256,512,2]  f32
// out:  [16,256,512,32] f32
//
// 2D-tiled: each 512-thread block = 8x8 pixel tile (8 threads/pixel, 4 floats/thread).
// Tiles ordered ty-fastest within a column strip; XCD swizzle makes vertically
// adjacent tiles run on the same XCD -> img rows shared between tiles hit L2.

typedef float floatx4 __attribute__((ext_vector_type(4)));

__global__ __launch_bounds__(512) void InvWarpFlow_kernel(
    const float* __restrict__ img,
    const float* __restrict__ flow,
    float* __restrict__ out)
{
    constexpr int H = 256, W = 512, C = 32;
    constexpr int TW = 8, TH = 8;                  // tile in pixels
    constexpr int TILES_Y = H / TH;                // 32
    constexpr int TILES_X = W / TW;                // 64
    constexpr int NBLK = 16 * TILES_X * TILES_Y;   // 32768
    constexpr int PER_XCD = NBLK / 8;              // 4096

    // XCD swizzle: consecutive logical ids land on the same XCD.
    int bid = blockIdx.x;
    int logical = (bid & 7) * PER_XCD + (bid >> 3);

    // Decode: ty fastest (vertical sweep), then tx, then batch.
    int ty   = logical & (TILES_Y - 1);
    int rest = logical >> 5;          // / TILES_Y
    int tx   = rest & (TILES_X - 1);
    int b    = rest >> 6;             // / TILES_X

    int t  = threadIdx.x;
    int cg = t & 7;                   // channel group (4 floats)
    int p  = t >> 3;                  // local pixel 0..63
    int lx = p & 7;
    int ly = p >> 3;

    int x = tx * TW + lx;
    int y = ty * TH + ly;
    int pix = ((b << 8) + y) * W + x; // b*H*W + y*W + x

    // flow[pix] = (dy, dx); query = grid + flow
    const float2 f = *reinterpret_cast<const float2*>(flow + (size_t)pix * 2);
    float qy = (float)y + f.x;
    float qx = (float)x + f.y;

    float fy = fminf(fmaxf(floorf(qy), 0.0f), (float)(H - 2));
    float fx = fminf(fmaxf(floorf(qx), 0.0f), (float)(W - 2));
    float ay = fminf(fmaxf(qy - fy, 0.0f), 1.0f);
    float ax = fminf(fmaxf(qx - fx, 0.0f), 1.0f);
    int iy = (int)fy;
    int ix = (int)fx;

    const float* base = img + ((((size_t)b * H + iy) * W + ix) * C) + cg * 4;
    floatx4 tl = *reinterpret_cast<const floatx4*>(base);
    floatx4 tr = *reinterpret_cast<const floatx4*>(base + C);
    floatx4 bl = *reinterpret_cast<const floatx4*>(base + (size_t)W * C);
    floatx4 br = *reinterpret_cast<const floatx4*>(base + (size_t)W * C + C);

    floatx4 top = tl + (tr - tl) * ax;
    floatx4 bot = bl + (br - bl) * ax;
    floatx4 o   = top + (bot - top) * ay;

    // Non-temporal store: keep the 256 MiB out-stream from evicting img in L2.
    __builtin_nontemporal_store(o, reinterpret_cast<floatx4*>(out + (size_t)pix * C + cg * 4));
}

extern "C" void kernel_launch(void* const* d_in, const int* in_sizes, int n_in,
                              void* d_out, int out_size, void* d_ws, size_t ws_size,
                              hipStream_t stream) {
    const float* img  = (const float*)d_in[0];
    const float* flow = (const float*)d_in[1];
    float* out = (float*)d_out;

    constexpr int NBLK = 32768;
    InvWarpFlow_kernel<<<NBLK, 512, 0, stream>>>(img, flow, out);
}

// Round 4
// 111.927 us; speedup vs baseline: 1.0482x; 1.0482x over previous
//
#include <hip/hip_runtime.h>

// InvWarpFlow: out[b,y,x,c] = bilinear(img[b], (y + flow[b,y,x,0], x + flow[b,y,x,1]))
// (reference is dense_image_warp(img, -flow), so query = grid + flow)
// img:  [16,256,512,32] f32 ; flow: [16,256,512,2] f32 ; out: [16,256,512,32] f32
//
// Latency-bound gather (R3 counters: HBM 33%, VALU 15%, occ 81%): the lever is
// memory-level parallelism. Each thread processes 4 pixels (4 rows of one
// 8x16 tile column): 4 flow loads issued upfront, then 16 independent img
// gathers in flight before the first use. Wave = 8 px x 8 cg -> every img/out
// access is 8 x 128B contiguous segments.

typedef float floatx4 __attribute__((ext_vector_type(4)));

__global__ __launch_bounds__(256) void InvWarpFlow_kernel(
    const float* __restrict__ img,
    const float* __restrict__ flow,
    float* __restrict__ out)
{
    constexpr int H = 256, W = 512, C = 32;
    constexpr int TW = 8, TH = 16;                  // tile in pixels
    constexpr int TILES_X = W / TW;                 // 64
    constexpr int TILES_Y = H / TH;                 // 16
    constexpr int NBLK = 16 * TILES_X * TILES_Y;    // 16384
    constexpr int PER_XCD = NBLK / 8;               // 2048

    // XCD-chunked swizzle; within a chunk tx varies fastest (band sweep).
    int bid = blockIdx.x;
    int logical = (bid & 7) * PER_XCD + (bid >> 3);

    int tx = logical & (TILES_X - 1);
    int r  = logical >> 6;
    int ty = r & (TILES_Y - 1);
    int b  = r >> 4;

    int t  = threadIdx.x;
    int cg = t & 7;                  // channel group (float4)
    int s  = t >> 3;                 // pixel slot 0..31
    int lx = s & 7;
    int wv = s >> 3;                 // wave id 0..3

    int x  = tx * TW + lx;
    int y0 = ty * TH + wv * 4;       // this thread's 4 rows: y0..y0+3
    int pix0 = ((b << 8) + y0) * W + x;

    // 4 independent flow loads, all issued before any use.
    float2 f[4];
    #pragma unroll
    for (int k = 0; k < 4; ++k)
        f[k] = *reinterpret_cast<const float2*>(flow + (size_t)(pix0 + k * W) * 2);

    const float* ib = img + (size_t)b * H * W * C + cg * 4;

    floatx4 tl[4], tr[4], bl[4], br[4];
    float ax[4], ay[4];
    #pragma unroll
    for (int k = 0; k < 4; ++k) {
        float qy = (float)(y0 + k) + f[k].x;
        float qx = (float)x + f[k].y;
        float fy = fminf(fmaxf(floorf(qy), 0.0f), (float)(H - 2));
        float fx = fminf(fmaxf(floorf(qx), 0.0f), (float)(W - 2));
        ay[k] = fminf(fmaxf(qy - fy, 0.0f), 1.0f);
        ax[k] = fminf(fmaxf(qx - fx, 0.0f), 1.0f);
        int iy = (int)fy;
        int ix = (int)fx;
        const float* base = ib + ((size_t)iy * W + ix) * C;
        tl[k] = *reinterpret_cast<const floatx4*>(base);
        tr[k] = *reinterpret_cast<const floatx4*>(base + C);
        bl[k] = *reinterpret_cast<const floatx4*>(base + (size_t)W * C);
        br[k] = *reinterpret_cast<const floatx4*>(base + (size_t)W * C + C);
    }

    #pragma unroll
    for (int k = 0; k < 4; ++k) {
        floatx4 top = tl[k] + (tr[k] - tl[k]) * ax[k];
        floatx4 bot = bl[k] + (br[k] - bl[k]) * ax[k];
        floatx4 o   = top + (bot - top) * ay[k];
        __builtin_nontemporal_store(
            o, reinterpret_cast<floatx4*>(out + (size_t)(pix0 + k * W) * C + cg * 4));
    }
}

extern "C" void kernel_launch(void* const* d_in, const int* in_sizes, int n_in,
                              void* d_out, int out_size, void* d_ws, size_t ws_size,
                              hipStream_t stream) {
    const float* img  = (const float*)d_in[0];
    const float* flow = (const float*)d_in[1];
    float* out = (float*)d_out;

    constexpr int NBLK = 16384;
    InvWarpFlow_kernel<<<NBLK, 256, 0, stream>>>(img, flow, out);
}